// Round 1
// baseline (222.792 us; speedup 1.0000x reference)
//
#include <hip/hip_runtime.h>
#include <math.h>

constexpr int kN = 20000;
constexpr int kD = 8;
constexpr int kE = 100000;
constexpr int kM = kN * 9;            // 180000 level-1 rows
constexpr int kTiles1 = kM / 16;      // 11250
constexpr int kTiles3 = kN / 16;      // 1250
constexpr float kEps = 1e-5f;

// stats float indices
constexpr int S_SUM1 = 0, S_SQ1 = 128, S_SUM2 = 256, S_SQ2 = 320;

// ws layout (bytes). Peak live = 51.2 MB (< proven 61.5 MB).
// Region M  [0,23.04M): prefix-means M[c][r] bf16 (k0 write, k1a read)
//   -> dead after k1a -> preHi (pre1 cols 64..127) written by k1b
//   -> dead after k3a -> pre2/embs/embsW.
// Region A1 [23.04M,46.08M): agg1 (frag-layout bf16, k1a write, k1b read)
//   -> overwritten IN-PLACE by k1b with pre1 cols 0..63 (row-major bf16;
//      safe: stores data-depend on the tile's own A-frag loads via MFMA)
//   -> dead after k3a.
constexpr size_t OFF_M     = 0;
constexpr size_t OFF_AGG1  = 23040000;
constexpr size_t OFF_AGG2  = 46080000;   // bf16 [kN][128] = 5.12 MB
constexpr size_t OFF_STATS = 51200000;   // 384 floats
constexpr size_t OFF_PRE2  = 0;          // f32 [kN][64] = 5.12 MB (reuse M)
constexpr size_t OFF_EMBS  = 5120000;
constexpr size_t OFF_EMBSW = 10240000;

typedef short short8 __attribute__((ext_vector_type(8)));
typedef float floatx4 __attribute__((ext_vector_type(4)));

__device__ __forceinline__ unsigned f2bf(float f) {  // f32 -> bf16 (RNE)
  unsigned u = __float_as_uint(f);
  u += 0x7fffu + ((u >> 16) & 1u);
  return u >> 16;
}

// ---------------------------------------------------------------------------
// K0: per-node prefix means. One wave per node c. Sort c's 8 neighbor ts
// (19-CE odd-even mergesort on wave-uniform scalars), then
//   M[c][r] = (x[c] + sum of r smallest-ts neighbors) / (r+1), r = 0..8.
// The level-1 masked mean for ANY query-ts t is then M[c][rank(t)] with
// rank(t) = #{j: nts[c,j] <= t} (ties adjacent in sorted order => exact).
// Reads 9 x-rows per NODE (20000) instead of per ROW (180000): 9x less.
// ---------------------------------------------------------------------------
__global__ __launch_bounds__(256) void k0_prefix(
    const float* __restrict__ x, const int* __restrict__ nidx,
    const float* __restrict__ nts, unsigned short* __restrict__ M)
{
  int c = blockIdx.x * 4 + (threadIdx.x >> 6);
  const int lane = threadIdx.x & 63;
  c = __builtin_amdgcn_readfirstlane(c);

  float ts[8]; int id[8];
#pragma unroll
  for (int j = 0; j < kD; ++j) { ts[j] = nts[c * kD + j]; id[j] = nidx[c * kD + j]; }

#define CSWAP(A, B)                                                   \
  { float ta = ts[A], tb = ts[B]; int ia = id[A], ib = id[B];         \
    bool sw = tb < ta;                                                \
    ts[A] = sw ? tb : ta; ts[B] = sw ? ta : tb;                       \
    id[A] = sw ? ib : ia; id[B] = sw ? ia : ib; }
  // sort [0..3]
  CSWAP(0, 1) CSWAP(2, 3) CSWAP(0, 2) CSWAP(1, 3) CSWAP(1, 2)
  // sort [4..7]
  CSWAP(4, 5) CSWAP(6, 7) CSWAP(4, 6) CSWAP(5, 7) CSWAP(5, 6)
  // odd-even merge
  CSWAP(0, 4) CSWAP(1, 5) CSWAP(2, 6) CSWAP(3, 7)
  CSWAP(2, 4) CSWAP(3, 5)
  CSWAP(1, 2) CSWAP(3, 4) CSWAP(5, 6)
#undef CSWAP

  float s = x[c * 64 + lane];
  unsigned short* mp = M + (size_t)c * 9 * 64 + lane;
  mp[0] = (unsigned short)f2bf(s);                    // rank 0: self only
#pragma unroll
  for (int r = 1; r <= kD; ++r) {
    s += x[id[r - 1] * 64 + lane];
    mp[r * 64] = (unsigned short)f2bf(s / (float)(r + 1));
  }
}

// ---------------------------------------------------------------------------
// K1a: one wave per level-1 row m. Compute rank of the row's query-ts among
// child c's neighbor ts (8 uniform compares), fetch the precomputed prefix
// mean M[c][rank] (one 128B row), store into MFMA A-FRAGMENT order:
//   addr(m,k) = (m/16)*1024 + (k/8)*128 + (m%16)*8 + (k%8)   [shorts]
// so k1b can read A-frags as coalesced 16B/lane global loads.
// ---------------------------------------------------------------------------
__global__ __launch_bounds__(256) void k1a_gather(
    const unsigned short* __restrict__ M, const float* __restrict__ node_ts,
    const int* __restrict__ nidx, const float* __restrict__ nts,
    unsigned short* __restrict__ agg1)
{
  const int m = blockIdx.x * 4 + (threadIdx.x >> 6);
  const int lane = threadIdx.x & 63;
  const int n = (int)((unsigned)m / 9u);
  const int slot = m - n * 9;
  int c; float t;
  if (slot < kD) { c = nidx[n * kD + slot]; t = nts[n * kD + slot]; }
  else           { c = n;                   t = node_ts[n]; }
  c = __builtin_amdgcn_readfirstlane(c);
  int rank = 0;
#pragma unroll
  for (int j = 0; j < kD; ++j) rank += (nts[c * kD + j] <= t) ? 1 : 0;
  unsigned short v = M[((size_t)c * 9 + rank) * 64 + lane];
  const int tt = m >> 4, r = m & 15, g = lane >> 3, jj = lane & 7;
  agg1[tt * 1024 + g * 128 + r * 8 + jj] = v;
}

// ---------------------------------------------------------------------------
// K1b: MFMA GEMM1. Wave per 16-row tile, A-frags straight from global
// (frag-ordered agg1, coalesced), B (W1^T) in padded LDS (stride 72 shorts
// -> 2-way bank alias = free). Stores pre1 split: cols 0..63 overwrite the
// tile's own agg1 (safe: stores data-depend on A-frag loads via MFMA),
// cols 64..127 to region M (dead). BN1 sum/sumsq block-reduced, atomic/col.
// ---------------------------------------------------------------------------
__global__ __launch_bounds__(256, 3) void k1b_gemm1(
    const unsigned short* aggA,          // region A1, frag layout (aliases preLo)
    unsigned short* preLo,               // region A1, rows x cols0..63 row-major
    unsigned short* __restrict__ preHi,  // region M, rows x cols64..127
    const float* __restrict__ W1, const float* __restrict__ b1,
    float* __restrict__ stats)
{
  __shared__ unsigned short W1T[128 * 72];   // padded: 2-way bank alias, free
  __shared__ float redS[256][8];
  __shared__ float redQ[256][8];

  const int tid = threadIdx.x;
  const int lane = tid & 63;
  const int wave = tid >> 6;
  const int l15 = lane & 15;
  const int q = lane >> 4;

  for (int i = tid; i < 8192; i += 256) {
    int n = i >> 6, k = i & 63;
    W1T[n * 72 + k] = (unsigned short)f2bf(W1[k * 128 + n]);
  }
  __syncthreads();

  short8 bf[8][2];
#pragma unroll
  for (int c = 0; c < 8; ++c)
#pragma unroll
    for (int s = 0; s < 2; ++s)
      bf[c][s] = *(const short8*)&W1T[(c * 16 + l15) * 72 + q * 8 + s * 32];

  float b1c[8];
#pragma unroll
  for (int c = 0; c < 8; ++c) b1c[c] = b1[c * 16 + l15];

  float sum8[8], sq8[8];
#pragma unroll
  for (int c = 0; c < 8; ++c) { sum8[c] = 0.f; sq8[c] = 0.f; }

  const int gw = blockIdx.x * 4 + wave;
  const int nw = gridDim.x * 4;

  for (int t = gw; t < kTiles1; t += nw) {
    const unsigned short* ap = aggA + (size_t)t * 1024;
    short8 af0 = *(const short8*)(ap + (q)*128 + l15 * 8);          // k in [0,32)
    short8 af1 = *(const short8*)(ap + (4 + q) * 128 + l15 * 8);    // k in [32,64)

    floatx4 acc[8];
#pragma unroll
    for (int c = 0; c < 8; ++c) {
      acc[c] = (floatx4){0.f, 0.f, 0.f, 0.f};
      acc[c] = __builtin_amdgcn_mfma_f32_16x16x32_bf16(af0, bf[c][0], acc[c], 0, 0, 0);
      acc[c] = __builtin_amdgcn_mfma_f32_16x16x32_bf16(af1, bf[c][1], acc[c], 0, 0, 0);
    }
#pragma unroll
    for (int c = 0; c < 8; ++c) {
      int colq = (c & 3) * 16 + l15;     // col within its 64-wide half
#pragma unroll
      for (int i = 0; i < 4; ++i) {
        float v = acc[c][i] + b1c[c];
        int row = t * 16 + q * 4 + i;
        unsigned short hv = (unsigned short)f2bf(v);
        if (c < 4) preLo[(size_t)row * 64 + colq] = hv;
        else       preHi[(size_t)row * 64 + colq] = hv;
        sum8[c] += v; sq8[c] += v * v;
      }
    }
  }

  __syncthreads();
#pragma unroll
  for (int c = 0; c < 8; ++c) { redS[tid][c] = sum8[c]; redQ[tid][c] = sq8[c]; }
  __syncthreads();
  if (tid < 128) {
    int c = tid >> 4, r15 = tid & 15;
    float s = 0.f, qq = 0.f;
#pragma unroll
    for (int w = 0; w < 4; ++w)
#pragma unroll
      for (int p = 0; p < 4; ++p) {
        int T = w * 64 + p * 16 + r15;
        s += redS[T][c]; qq += redQ[T][c];
      }
    atomicAdd(&stats[S_SUM1 + tid], s);
    atomicAdd(&stats[S_SQ1 + tid], qq);
  }
}

// ---------------------------------------------------------------------------
// K3a: (BN1 finalize folded in) BN1+ReLU on split pre1, masked mean over 9
// slots -> agg2 bf16 [kN][128] row-major. One wave per node, lane = col pair.
// ---------------------------------------------------------------------------
__global__ __launch_bounds__(256) void k3a_agg2(
    const unsigned* __restrict__ loDW, const unsigned* __restrict__ hiDW,
    const float* __restrict__ node_ts, const float* __restrict__ nts,
    const float* __restrict__ stats, const float* __restrict__ g1,
    const float* __restrict__ be1, unsigned* __restrict__ agg2dw)
{
  __shared__ float sc[128], sh[128];
  const int tid = threadIdx.x;
  if (tid < 128) {
    float mean = stats[S_SUM1 + tid] * (1.f / kM);
    float var  = stats[S_SQ1 + tid] * (1.f / kM) - mean * mean;
    float s    = g1[tid] * rsqrtf(var + kEps);
    sc[tid] = s; sh[tid] = be1[tid] - mean * s;
  }
  __syncthreads();
  const int n = blockIdx.x * 4 + (tid >> 6);
  const int L = tid & 63;
  const unsigned* base = (L < 32) ? loDW : hiDW;
  const int Lc = L & 31;
  const float sc0 = sc[2 * L], sc1 = sc[2 * L + 1];
  const float sh0 = sh[2 * L], sh1 = sh[2 * L + 1];
  const float tn = node_ts[n];
  float s0 = 0.f, s1 = 0.f, fcnt = 0.f;
#pragma unroll
  for (int slot = 0; slot < 9; ++slot) {
    float w = (slot < kD) ? ((nts[n * kD + slot] <= tn) ? 1.f : 0.f) : 1.f;
    unsigned u = base[(size_t)(n * 9 + slot) * 32 + Lc];
    float p0 = __uint_as_float(u << 16);
    float p1 = __uint_as_float(u & 0xffff0000u);
    s0 += w * fmaxf(fmaf(p0, sc0, sh0), 0.f);
    s1 += w * fmaxf(fmaf(p1, sc1, sh1), 0.f);
    fcnt += w;
  }
  float r = 1.f / fcnt;
  agg2dw[n * 64 + L] = f2bf(s0 * r) | (f2bf(s1 * r) << 16);
}

// ---------------------------------------------------------------------------
// K3b: MFMA GEMM2: agg2 [N][128] x W2 [128][64] + b2 -> pre2 f32, BN2 stats.
// ---------------------------------------------------------------------------
__global__ __launch_bounds__(256, 3) void k3b_gemm2(
    const unsigned short* __restrict__ agg2, const float* __restrict__ W2,
    const float* __restrict__ b2, float* __restrict__ stats,
    float* __restrict__ pre2)
{
  __shared__ unsigned short W2T[64 * 136];   // padded leading dim
  __shared__ float redS[256][4];
  __shared__ float redQ[256][4];

  const int tid = threadIdx.x;
  const int lane = tid & 63;
  const int wave = tid >> 6;
  const int l15 = lane & 15;
  const int q = lane >> 4;

  for (int i = tid; i < 8192; i += 256) {
    int n = i >> 7, k = i & 127;
    W2T[n * 136 + k] = (unsigned short)f2bf(W2[k * 64 + n]);
  }
  __syncthreads();

  short8 bfr[4][4];
#pragma unroll
  for (int c = 0; c < 4; ++c)
#pragma unroll
    for (int s = 0; s < 4; ++s)
      bfr[c][s] = *(const short8*)&W2T[(c * 16 + l15) * 136 + q * 8 + s * 32];

  float b2c[4];
#pragma unroll
  for (int c = 0; c < 4; ++c) b2c[c] = b2[c * 16 + l15];

  float sum4[4], sq4[4];
#pragma unroll
  for (int c = 0; c < 4; ++c) { sum4[c] = 0.f; sq4[c] = 0.f; }

  const int gw = blockIdx.x * 4 + wave;
  const int nw = gridDim.x * 4;

  for (int t = gw; t < kTiles3; t += nw) {
    const int r0 = t * 16;
    short8 af[4];
#pragma unroll
    for (int s = 0; s < 4; ++s)
      af[s] = *(const short8*)&agg2[(size_t)(r0 + l15) * 128 + q * 8 + s * 32];

    floatx4 acc[4];
#pragma unroll
    for (int c = 0; c < 4; ++c) {
      acc[c] = (floatx4){0.f, 0.f, 0.f, 0.f};
#pragma unroll
      for (int s = 0; s < 4; ++s)
        acc[c] = __builtin_amdgcn_mfma_f32_16x16x32_bf16(af[s], bfr[c][s], acc[c], 0, 0, 0);
    }
#pragma unroll
    for (int c = 0; c < 4; ++c) {
      int col = c * 16 + l15;
#pragma unroll
      for (int i = 0; i < 4; ++i) {
        float v = acc[c][i] + b2c[c];
        int row = r0 + q * 4 + i;
        pre2[(size_t)row * 64 + col] = v;
        sum4[c] += v; sq4[c] += v * v;
      }
    }
  }

  __syncthreads();
#pragma unroll
  for (int c = 0; c < 4; ++c) { redS[tid][c] = sum4[c]; redQ[tid][c] = sq4[c]; }
  __syncthreads();
  if (tid < 64) {
    int c = tid >> 4, r15 = tid & 15;
    float s = 0.f, qq = 0.f;
#pragma unroll
    for (int w = 0; w < 4; ++w)
#pragma unroll
      for (int p = 0; p < 4; ++p) {
        int T = w * 64 + p * 16 + r15;
        s += redS[T][c]; qq += redQ[T][c];
      }
    atomicAdd(&stats[S_SUM2 + tid], s);
    atomicAdd(&stats[S_SQ2 + tid], qq);
  }
}

// K5: (BN2 finalize folded in) embs = relu(BN2(pre2)); embsW = embs * Wd.
__global__ __launch_bounds__(256) void k5_embs(
    const float* __restrict__ pre2, const float* __restrict__ stats,
    const float* __restrict__ g2, const float* __restrict__ be2,
    const float* __restrict__ Wd, float* __restrict__ embs,
    float* __restrict__ embsW)
{
  __shared__ float sc[64], sh[64], wd[64];
  const int tid = threadIdx.x;
  if (tid < 64) {
    float mean = stats[S_SUM2 + tid] * (1.f / kN);
    float var  = stats[S_SQ2 + tid] * (1.f / kN) - mean * mean;
    float s    = g2[tid] * rsqrtf(var + kEps);
    sc[tid] = s; sh[tid] = be2[tid] - mean * s; wd[tid] = Wd[tid];
  }
  __syncthreads();
  int idx = blockIdx.x * 256 + tid;   // grid exact kN*64/256
  int col = idx & 63;
  float e = fmaxf(fmaf(pre2[idx], sc[col], sh[col]), 0.f);
  embs[idx] = e;
  embsW[idx] = e * wd[col];
}

// K6: quarter-wave (16 lanes) per pair, 8 pairs per quarter. Coalesced 256B
// row reads, shfl_xor butterfly dot-reduce, block LDS reduce, one atomic.
__global__ __launch_bounds__(256) void k6_loss(
    const float* __restrict__ embs, const float* __restrict__ embsW,
    const int* __restrict__ tgt, const int* __restrict__ neg,
    const float* __restrict__ bd, float* __restrict__ out)
{
  __shared__ float redl[256];
  const int tid = threadIdx.x;
  const int tq = tid & 15;
  const int qb = tid >> 4;           // 16 quarters per block
  const float bd0 = bd[0];
  float lsum = 0.f;
  const int e0 = blockIdx.x * 128 + qb * 8;
#pragma unroll
  for (int it = 0; it < 8; ++it) {
    int e = e0 + it;
    if (e < 2 * kE) {
      int i, j; float lab;
      if (e < kE) { i = tgt[e];      j = tgt[kE + e]; lab = 1.f; }
      else        { i = neg[e - kE]; j = neg[e];      lab = 0.f; }
      float4 av = *(const float4*)(embsW + (size_t)i * 64 + tq * 4);
      float4 bv = *(const float4*)(embs  + (size_t)j * 64 + tq * 4);
      float p = av.x * bv.x + av.y * bv.y + av.z * bv.z + av.w * bv.w;
      p += __shfl_xor(p, 1); p += __shfl_xor(p, 2);
      p += __shfl_xor(p, 4); p += __shfl_xor(p, 8);
      p += bd0;
      float l = fmaxf(p, 0.f) - p * lab + log1pf(expf(-fabsf(p)));
      if (tq == 0) lsum += l;
    }
  }
  redl[tid] = lsum;
  __syncthreads();
  for (int s = 128; s > 0; s >>= 1) {
    if (tid < s) redl[tid] += redl[tid + s];
    __syncthreads();
  }
  if (tid == 0) atomicAdd(out, redl[0] * (1.f / (2 * kE)));
}

extern "C" void kernel_launch(void* const* d_in, const int* in_sizes, int n_in,
                              void* d_out, int out_size, void* d_ws, size_t ws_size,
                              hipStream_t stream) {
  (void)in_sizes; (void)n_in; (void)out_size; (void)ws_size;
  const float* x       = (const float*)d_in[0];
  const float* node_ts = (const float*)d_in[1];
  const int*   nidx    = (const int*)d_in[2];
  const float* nts     = (const float*)d_in[3];
  const int*   tgt     = (const int*)d_in[4];
  const int*   neg     = (const int*)d_in[5];
  const float* W1      = (const float*)d_in[6];
  const float* b1      = (const float*)d_in[7];
  const float* g1      = (const float*)d_in[8];
  const float* be1     = (const float*)d_in[9];
  const float* W2      = (const float*)d_in[10];
  const float* b2      = (const float*)d_in[11];
  const float* g2      = (const float*)d_in[12];
  const float* be2     = (const float*)d_in[13];
  const float* Wd      = (const float*)d_in[14];
  const float* bd      = (const float*)d_in[15];

  char* ws = (char*)d_ws;
  unsigned short* Mbuf  = (unsigned short*)(ws + OFF_M);     // prefix means / preHi
  unsigned short* agg1  = (unsigned short*)(ws + OFF_AGG1);  // agg1 frag / preLo
  unsigned short* agg2  = (unsigned short*)(ws + OFF_AGG2);
  float* stats = (float*)(ws + OFF_STATS);
  float* pre2  = (float*)(ws + OFF_PRE2);
  float* embs  = (float*)(ws + OFF_EMBS);
  float* embsW = (float*)(ws + OFF_EMBSW);
  float* out   = (float*)d_out;

  hipMemsetAsync(stats, 0, 384 * sizeof(float), stream);
  hipMemsetAsync(out, 0, sizeof(float), stream);

  k0_prefix<<<kN / 4, 256, 0, stream>>>(x, nidx, nts, Mbuf);
  k1a_gather<<<kM / 4, 256, 0, stream>>>(Mbuf, node_ts, nidx, nts, agg1);
  k1b_gemm1<<<704, 256, 0, stream>>>(agg1, agg1, Mbuf, W1, b1, stats);
  k3a_agg2<<<kN / 4, 256, 0, stream>>>((const unsigned*)agg1, (const unsigned*)Mbuf,
                                       node_ts, nts, stats, g1, be1, (unsigned*)agg2);
  k3b_gemm2<<<160, 256, 0, stream>>>(agg2, W2, b2, stats, pre2);
  k5_embs<<<kN * 64 / 256, 256, 0, stream>>>(pre2, stats, g2, be2, Wd, embs, embsW);
  k6_loss<<<(2 * kE + 127) / 128, 256, 0, stream>>>(embs, embsW, tgt, neg, bd, out);
}

// Round 2
// 207.125 us; speedup vs baseline: 1.0756x; 1.0756x over previous
//
#include <hip/hip_runtime.h>
#include <math.h>

constexpr int kN = 20000;
constexpr int kD = 8;
constexpr int kE = 100000;
constexpr int kM = kN * 9;            // 180000 level-1 rows (== M rows)
constexpr int kTiles1 = kM / 16;      // 11250 M-row tiles
constexpr int kTilesN = kN / 16;      // 1250 node tiles
constexpr float kEps = 1e-5f;

// stats float indices
constexpr int S_SUM1 = 0, S_SQ1 = 128, S_SUM2 = 256, S_SQ2 = 320;

// ws layout (bytes). Peak live ~29.6 MB.
// M (prefix means, bf16 [180000][64]) lives until k3_fused completes.
constexpr size_t OFF_M     = 0;                    // 23.04 MB
constexpr size_t OFF_PRE2  = 23040000;             // f32 [kN][64] = 5.12 MB
constexpr size_t OFF_STATS = 28160000;             // 384 f32
constexpr size_t OFF_CNT   = OFF_STATS + 1536;     // f32 [180000] = 0.72 MB
constexpr size_t OFF_RI    = OFF_CNT + 720000;     // i32 [180000] = 0.72 MB

typedef short short8 __attribute__((ext_vector_type(8)));
typedef float floatx4 __attribute__((ext_vector_type(4)));

__device__ __forceinline__ unsigned f2bf(float f) {  // f32 -> bf16 (RNE)
  unsigned u = __float_as_uint(f);
  u += 0x7fffu + ((u >> 16) & 1u);
  return u >> 16;
}

// ---------------------------------------------------------------------------
// K0: (a) per-node prefix means M[c][r] = mean of {x[c]} U {r smallest-ts
// neighbors of c}, one wave per node (19-CE sort of 8 wave-uniform scalars);
// (b) per level-1 row m: rowinfo[m] = c*9 + rank (which M row it uses) and
// cnt[c*9+rank] += 1 (multiplicity for the BN1 stats pass). One thread/row.
// ---------------------------------------------------------------------------
__global__ __launch_bounds__(256) void k0_prefix(
    const float* __restrict__ x, const float* __restrict__ node_ts,
    const int* __restrict__ nidx, const float* __restrict__ nts,
    unsigned short* __restrict__ M, int* __restrict__ rowinfo,
    float* __restrict__ cntf)
{
  // ---- part 1: prefix means (wave per node) ----
  int c = blockIdx.x * 4 + (threadIdx.x >> 6);
  const int lane = threadIdx.x & 63;
  c = __builtin_amdgcn_readfirstlane(c);

  float ts[8]; int id[8];
#pragma unroll
  for (int j = 0; j < kD; ++j) { ts[j] = nts[c * kD + j]; id[j] = nidx[c * kD + j]; }

#define CSWAP(A, B)                                                   \
  { float ta = ts[A], tb = ts[B]; int ia = id[A], ib = id[B];         \
    bool sw = tb < ta;                                                \
    ts[A] = sw ? tb : ta; ts[B] = sw ? ta : tb;                       \
    id[A] = sw ? ib : ia; id[B] = sw ? ia : ib; }
  CSWAP(0, 1) CSWAP(2, 3) CSWAP(0, 2) CSWAP(1, 3) CSWAP(1, 2)
  CSWAP(4, 5) CSWAP(6, 7) CSWAP(4, 6) CSWAP(5, 7) CSWAP(5, 6)
  CSWAP(0, 4) CSWAP(1, 5) CSWAP(2, 6) CSWAP(3, 7)
  CSWAP(2, 4) CSWAP(3, 5)
  CSWAP(1, 2) CSWAP(3, 4) CSWAP(5, 6)
#undef CSWAP

  float s = x[c * 64 + lane];
  unsigned short* mp = M + (size_t)c * 9 * 64 + lane;
  mp[0] = (unsigned short)f2bf(s);
#pragma unroll
  for (int r = 1; r <= kD; ++r) {
    s += x[id[r - 1] * 64 + lane];
    mp[r * 64] = (unsigned short)f2bf(s / (float)(r + 1));
  }

  // ---- part 2: rowinfo + counts (thread per row; first 704 blocks) ----
  const int m = blockIdx.x * 256 + threadIdx.x;
  if (m < kM) {
    const int n = (int)((unsigned)m / 9u);
    const int slot = m - n * 9;
    int cc; float t;
    if (slot < kD) { cc = nidx[n * kD + slot]; t = nts[n * kD + slot]; }
    else           { cc = n;                   t = node_ts[n]; }
    int rank = 0;
#pragma unroll
    for (int j = 0; j < kD; ++j) rank += (nts[cc * kD + j] <= t) ? 1 : 0;
    rowinfo[m] = cc * 9 + rank;
    atomicAdd(&cntf[cc * 9 + rank], 1.0f);
  }
}

// ---------------------------------------------------------------------------
// K1: BN1 stats WITHOUT materializing pre1. Streams M's 180000 rows
// (coalesced), GEMM1 per 16-row tile, weights each row's contribution by
// cnt[row] (its multiplicity among the 180000 level-1 rows). No stores
// except the final block-reduced atomics.
// ---------------------------------------------------------------------------
__global__ __launch_bounds__(256, 3) void k1_stats(
    const unsigned short* __restrict__ M, const float* __restrict__ cntf,
    const float* __restrict__ W1, const float* __restrict__ b1,
    float* __restrict__ stats)
{
  __shared__ unsigned short W1T[128 * 72];   // padded: 2-way bank alias, free
  __shared__ float redS[256][8];
  __shared__ float redQ[256][8];

  const int tid = threadIdx.x;
  const int lane = tid & 63;
  const int wave = tid >> 6;
  const int l15 = lane & 15;
  const int q = lane >> 4;

  for (int i = tid; i < 8192; i += 256) {
    int n = i >> 6, k = i & 63;
    W1T[n * 72 + k] = (unsigned short)f2bf(W1[k * 128 + n]);
  }
  __syncthreads();

  short8 bf[8][2];
#pragma unroll
  for (int cc = 0; cc < 8; ++cc)
#pragma unroll
    for (int s = 0; s < 2; ++s)
      bf[cc][s] = *(const short8*)&W1T[(cc * 16 + l15) * 72 + q * 8 + s * 32];

  float b1c[8];
#pragma unroll
  for (int cc = 0; cc < 8; ++cc) b1c[cc] = b1[cc * 16 + l15];

  float sum8[8], sq8[8];
#pragma unroll
  for (int cc = 0; cc < 8; ++cc) { sum8[cc] = 0.f; sq8[cc] = 0.f; }

  const int gw = blockIdx.x * 4 + wave;
  const int nw = gridDim.x * 4;

  for (int t = gw; t < kTiles1; t += nw) {
    const unsigned short* mp = M + (size_t)(t * 16 + l15) * 64;
    short8 af0 = *(const short8*)(mp + q * 8);         // k in [0,32)
    short8 af1 = *(const short8*)(mp + 32 + q * 8);    // k in [32,64)
    float c4[4];
#pragma unroll
    for (int i = 0; i < 4; ++i) c4[i] = cntf[t * 16 + q * 4 + i];

    floatx4 acc[8];
#pragma unroll
    for (int cc = 0; cc < 8; ++cc) {
      acc[cc] = (floatx4){0.f, 0.f, 0.f, 0.f};
      acc[cc] = __builtin_amdgcn_mfma_f32_16x16x32_bf16(af0, bf[cc][0], acc[cc], 0, 0, 0);
      acc[cc] = __builtin_amdgcn_mfma_f32_16x16x32_bf16(af1, bf[cc][1], acc[cc], 0, 0, 0);
    }
#pragma unroll
    for (int cc = 0; cc < 8; ++cc) {
#pragma unroll
      for (int i = 0; i < 4; ++i) {
        float v = acc[cc][i] + b1c[cc];
        sum8[cc] += c4[i] * v;
        sq8[cc]  += c4[i] * v * v;
      }
    }
  }

  __syncthreads();
#pragma unroll
  for (int cc = 0; cc < 8; ++cc) { redS[tid][cc] = sum8[cc]; redQ[tid][cc] = sq8[cc]; }
  __syncthreads();
  if (tid < 128) {
    int cc = tid >> 4, r15 = tid & 15;
    float s = 0.f, qq = 0.f;
#pragma unroll
    for (int w = 0; w < 4; ++w)
#pragma unroll
      for (int p = 0; p < 4; ++p) {
        int T = w * 64 + p * 16 + r15;
        s += redS[T][cc]; qq += redQ[T][cc];
      }
    atomicAdd(&stats[S_SUM1 + tid], s);
    atomicAdd(&stats[S_SQ1 + tid], qq);
  }
}

// ---------------------------------------------------------------------------
// K3: FUSED layer-1-recompute + BN1 + ReLU + masked-mean + GEMM2 + BN2 stats.
// Block = 16 nodes = 144 rows = 9 MFMA row-tiles.
//  ph2: mask weights for the 144 rows -> wlds, winv (1/sum per node)
//  ph3: GEMM1 from M[rowinfo[...]] gathers -> BN1+ReLU+weight -> sm (bf16)
//  ph5: reduce 9 slots per node -> agg2 tile (bf16) in aggT
//  ph7: GEMM2 (aggT x W2T) -> pre2 (f32, global) + per-lane BN2 partials
// pre1 and agg2 never touch HBM. LDS ~78 KB -> 2 blocks/CU.
// ---------------------------------------------------------------------------
__global__ __launch_bounds__(256, 2) void k3_fused(
    const unsigned short* __restrict__ M, const int* __restrict__ rowinfo,
    const float* __restrict__ node_ts, const float* __restrict__ nts,
    const float* __restrict__ stats_in, const float* __restrict__ g1,
    const float* __restrict__ be1, const float* __restrict__ W1,
    const float* __restrict__ b1, const float* __restrict__ W2,
    const float* __restrict__ b2, float* __restrict__ stats_out,
    float* __restrict__ pre2)
{
  __shared__ __attribute__((aligned(16))) unsigned short W1T[128 * 72];
  __shared__ __attribute__((aligned(16))) unsigned short W2T[64 * 136];
  __shared__ __attribute__((aligned(16))) unsigned short sm[144 * 132];
  __shared__ __attribute__((aligned(16))) unsigned short aggT[16 * 136];
  __shared__ float sc1[128], sh1[128];
  __shared__ float wlds[144];
  __shared__ float winv[16];

  const int tid = threadIdx.x;
  const int lane = tid & 63;
  const int wave = tid >> 6;
  const int l15 = lane & 15;
  const int q = lane >> 4;

  for (int i = tid; i < 8192; i += 256) {
    int n = i >> 6, k = i & 63;
    W1T[n * 72 + k] = (unsigned short)f2bf(W1[k * 128 + n]);
  }
  for (int i = tid; i < 8192; i += 256) {
    int n = i >> 7, k = i & 127;
    W2T[n * 136 + k] = (unsigned short)f2bf(W2[k * 64 + n]);
  }
  if (tid < 128) {
    float mean = stats_in[S_SUM1 + tid] * (1.f / kM);
    float var  = stats_in[S_SQ1 + tid] * (1.f / kM) - mean * mean;
    float s    = g1[tid] * rsqrtf(var + kEps);
    sc1[tid] = s; sh1[tid] = be1[tid] - mean * s;
  }
  __syncthreads();

  // per-lane constants (fixed columns across all tiles)
  short8 bf[8][2];
  float b1c[8], scc[8], shc[8];
#pragma unroll
  for (int cc = 0; cc < 8; ++cc) {
    int col = cc * 16 + l15;
#pragma unroll
    for (int s = 0; s < 2; ++s)
      bf[cc][s] = *(const short8*)&W1T[col * 72 + q * 8 + s * 32];
    b1c[cc] = b1[col]; scc[cc] = sc1[col]; shc[cc] = sh1[col];
  }
  short8 bfr2[4];
#pragma unroll
  for (int s = 0; s < 4; ++s)
    bfr2[s] = *(const short8*)&W2T[(wave * 16 + l15) * 136 + q * 8 + s * 32];
  const float b2w = b2[wave * 16 + l15];

  float sumS = 0.f, sumQ = 0.f;   // BN2 partials, col = wave*16+l15

  for (int tb = blockIdx.x; tb < kTilesN; tb += gridDim.x) {
    const int node0 = tb * 16;
    const int row0 = tb * 144;

    // ph2: mask weights
    if (tid < 144) {
      int ln = tid / 9;
      int slot = tid - ln * 9;
      int nn = node0 + ln;
      float w = 1.f;
      if (slot < kD) w = (nts[nn * kD + slot] <= node_ts[nn]) ? 1.f : 0.f;
      wlds[tid] = w;
    }
    __syncthreads();                               // B1
    if (tid < 16) {
      float swv = 0.f;
#pragma unroll
      for (int r = 0; r < 9; ++r) swv += wlds[tid * 9 + r];
      winv[tid] = 1.f / swv;
    }

    // ph3: GEMM1 recompute -> BN1+ReLU+weight -> sm (bf16)
    for (int tl = wave; tl < 9; tl += 4) {
      const int ri = rowinfo[row0 + tl * 16 + l15];
      const unsigned short* mp = M + (size_t)ri * 64;
      short8 af0 = *(const short8*)(mp + q * 8);
      short8 af1 = *(const short8*)(mp + 32 + q * 8);
      floatx4 acc[8];
#pragma unroll
      for (int cc = 0; cc < 8; ++cc) {
        acc[cc] = (floatx4){0.f, 0.f, 0.f, 0.f};
        acc[cc] = __builtin_amdgcn_mfma_f32_16x16x32_bf16(af0, bf[cc][0], acc[cc], 0, 0, 0);
        acc[cc] = __builtin_amdgcn_mfma_f32_16x16x32_bf16(af1, bf[cc][1], acc[cc], 0, 0, 0);
      }
#pragma unroll
      for (int cc = 0; cc < 8; ++cc) {
        int col = cc * 16 + l15;
#pragma unroll
        for (int i = 0; i < 4; ++i) {
          float v = acc[cc][i] + b1c[cc];
          float val = fmaxf(fmaf(v, scc[cc], shc[cc]), 0.f);
          int rl = tl * 16 + q * 4 + i;
          val *= wlds[rl];
          sm[rl * 132 + col] = (unsigned short)f2bf(val);
        }
      }
    }
    __syncthreads();                               // B2

    // ph5: 9-slot reduce -> aggT (16 agg2 rows, bf16-pair packed)
#pragma unroll
    for (int k = 0; k < 4; ++k) {
      int it = tid + k * 256;        // 0..1023: (node, colpair)
      int nd = it >> 6, cp = it & 63;
      float s0 = 0.f, s1 = 0.f;
#pragma unroll
      for (int r = 0; r < 9; ++r) {
        unsigned u = *(const unsigned*)&sm[(nd * 9 + r) * 132 + cp * 2];
        s0 += __uint_as_float(u << 16);
        s1 += __uint_as_float(u & 0xffff0000u);
      }
      float iv = winv[nd];
      *(unsigned*)&aggT[nd * 136 + cp * 2] = f2bf(s0 * iv) | (f2bf(s1 * iv) << 16);
    }
    __syncthreads();                               // B3

    // ph7: GEMM2 for this node tile; wave handles cols wave*16..wave*16+15
    short8 af2[4];
#pragma unroll
    for (int s = 0; s < 4; ++s)
      af2[s] = *(const short8*)&aggT[l15 * 136 + q * 8 + s * 32];
    floatx4 acc2 = (floatx4){0.f, 0.f, 0.f, 0.f};
#pragma unroll
    for (int s = 0; s < 4; ++s)
      acc2 = __builtin_amdgcn_mfma_f32_16x16x32_bf16(af2[s], bfr2[s], acc2, 0, 0, 0);
#pragma unroll
    for (int i = 0; i < 4; ++i) {
      float v = acc2[i] + b2w;
      int nrow = node0 + q * 4 + i;
      pre2[(size_t)nrow * 64 + wave * 16 + l15] = v;
      sumS += v; sumQ += v * v;
    }
    // no barrier: next iteration's B1 orders sm/aggT/wlds reuse.
  }

  // BN2 stats: combine the 4 q-groups (same col), one atomic per col pair
  sumS += __shfl_xor(sumS, 16); sumS += __shfl_xor(sumS, 32);
  sumQ += __shfl_xor(sumQ, 16); sumQ += __shfl_xor(sumQ, 32);
  if (lane < 16) {
    atomicAdd(&stats_out[S_SUM2 + wave * 16 + lane], sumS);
    atomicAdd(&stats_out[S_SQ2 + wave * 16 + lane], sumQ);
  }
}

// ---------------------------------------------------------------------------
// K6: loss with BN2+ReLU+Wd applied INLINE on gathered pre2 rows (embs never
// materialized; working set 5.12 MB -> L2-friendly). Quarter-wave per pair.
// ---------------------------------------------------------------------------
__global__ __launch_bounds__(256) void k6_loss(
    const float* __restrict__ pre2, const float* __restrict__ stats,
    const float* __restrict__ g2, const float* __restrict__ be2,
    const float* __restrict__ Wd, const int* __restrict__ tgt,
    const int* __restrict__ neg, const float* __restrict__ bd,
    float* __restrict__ out)
{
  __shared__ float scl[64], shl[64], wdl[64];
  __shared__ float redl[256];
  const int tid = threadIdx.x;
  if (tid < 64) {
    float mean = stats[S_SUM2 + tid] * (1.f / kN);
    float var  = stats[S_SQ2 + tid] * (1.f / kN) - mean * mean;
    float s    = g2[tid] * rsqrtf(var + kEps);
    scl[tid] = s; shl[tid] = be2[tid] - mean * s; wdl[tid] = Wd[tid];
  }
  __syncthreads();

  const int tq = tid & 15;
  const int qb = tid >> 4;
  const int c0 = tq * 4;
  const float4 sc4 = {scl[c0], scl[c0 + 1], scl[c0 + 2], scl[c0 + 3]};
  const float4 sh4 = {shl[c0], shl[c0 + 1], shl[c0 + 2], shl[c0 + 3]};
  const float4 wd4 = {wdl[c0], wdl[c0 + 1], wdl[c0 + 2], wdl[c0 + 3]};
  const float bd0 = bd[0];

  float lsum = 0.f;
  const int e0 = blockIdx.x * 128 + qb * 8;
#pragma unroll
  for (int it = 0; it < 8; ++it) {
    int e = e0 + it;
    if (e < 2 * kE) {
      int i, j; float lab;
      if (e < kE) { i = tgt[e];      j = tgt[kE + e]; lab = 1.f; }
      else        { i = neg[e - kE]; j = neg[e];      lab = 0.f; }
      float4 a = *(const float4*)(pre2 + (size_t)i * 64 + c0);
      float4 b = *(const float4*)(pre2 + (size_t)j * 64 + c0);
      float eix = fmaxf(fmaf(a.x, sc4.x, sh4.x), 0.f) * wd4.x;
      float eiy = fmaxf(fmaf(a.y, sc4.y, sh4.y), 0.f) * wd4.y;
      float eiz = fmaxf(fmaf(a.z, sc4.z, sh4.z), 0.f) * wd4.z;
      float eiw = fmaxf(fmaf(a.w, sc4.w, sh4.w), 0.f) * wd4.w;
      float ejx = fmaxf(fmaf(b.x, sc4.x, sh4.x), 0.f);
      float ejy = fmaxf(fmaf(b.y, sc4.y, sh4.y), 0.f);
      float ejz = fmaxf(fmaf(b.z, sc4.z, sh4.z), 0.f);
      float ejw = fmaxf(fmaf(b.w, sc4.w, sh4.w), 0.f);
      float p = eix * ejx + eiy * ejy + eiz * ejz + eiw * ejw;
      p += __shfl_xor(p, 1); p += __shfl_xor(p, 2);
      p += __shfl_xor(p, 4); p += __shfl_xor(p, 8);
      p += bd0;
      float l = fmaxf(p, 0.f) - p * lab + log1pf(expf(-fabsf(p)));
      if (tq == 0) lsum += l;
    }
  }
  redl[tid] = lsum;
  __syncthreads();
  for (int s = 128; s > 0; s >>= 1) {
    if (tid < s) redl[tid] += redl[tid + s];
    __syncthreads();
  }
  if (tid == 0) atomicAdd(out, redl[0] * (1.f / (2 * kE)));
}

extern "C" void kernel_launch(void* const* d_in, const int* in_sizes, int n_in,
                              void* d_out, int out_size, void* d_ws, size_t ws_size,
                              hipStream_t stream) {
  (void)in_sizes; (void)n_in; (void)out_size; (void)ws_size;
  const float* x       = (const float*)d_in[0];
  const float* node_ts = (const float*)d_in[1];
  const int*   nidx    = (const int*)d_in[2];
  const float* nts     = (const float*)d_in[3];
  const int*   tgt     = (const int*)d_in[4];
  const int*   neg     = (const int*)d_in[5];
  const float* W1      = (const float*)d_in[6];
  const float* b1      = (const float*)d_in[7];
  const float* g1      = (const float*)d_in[8];
  const float* be1     = (const float*)d_in[9];
  const float* W2      = (const float*)d_in[10];
  const float* b2      = (const float*)d_in[11];
  const float* g2      = (const float*)d_in[12];
  const float* be2     = (const float*)d_in[13];
  const float* Wd      = (const float*)d_in[14];
  const float* bd      = (const float*)d_in[15];

  char* ws = (char*)d_ws;
  unsigned short* Mbuf = (unsigned short*)(ws + OFF_M);
  float* pre2  = (float*)(ws + OFF_PRE2);
  float* stats = (float*)(ws + OFF_STATS);
  float* cntf  = (float*)(ws + OFF_CNT);
  int*   rinfo = (int*)(ws + OFF_RI);
  float* out   = (float*)d_out;

  // zero stats + counts in one memset (contiguous)
  hipMemsetAsync(stats, 0, 1536 + 720000, stream);
  hipMemsetAsync(out, 0, sizeof(float), stream);

  k0_prefix<<<kN / 4, 256, 0, stream>>>(x, node_ts, nidx, nts, Mbuf, rinfo, cntf);
  k1_stats<<<704, 256, 0, stream>>>(Mbuf, cntf, W1, b1, stats);
  k3_fused<<<512, 256, 0, stream>>>(Mbuf, rinfo, node_ts, nts, stats, g1, be1,
                                    W1, b1, W2, b2, stats, pre2);
  k6_loss<<<(2 * kE + 127) / 128, 256, 0, stream>>>(pre2, stats, g2, be2, Wd,
                                                    tgt, neg, bd, out);
}